// Round 2
// baseline (15347.440 us; speedup 1.0000x reference)
//
#include <hip/hip_runtime.h>
#include <hip/hip_bf16.h>
#include <stdint.h>

// LSTM: S=1024, B=64, D=1024, H=1024. fp32 in/out, bf16 MFMA internally.
// out = [Yt (S*B*H) | hT (B*H) | cT (B*H)] fp32.

#define NWG 128

typedef __attribute__((ext_vector_type(8))) short bf16x8;
typedef __attribute__((ext_vector_type(4))) float f32x4;

__device__ __forceinline__ unsigned short f2bf(float f) {
    unsigned u = __builtin_bit_cast(unsigned, f);
    return (unsigned short)((u + 0x7fffu + ((u >> 16) & 1u)) >> 16);
}

// ---------------- init: bias fusion + state zeroing ----------------
__global__ void init_kernel(const float* __restrict__ iiB, const float* __restrict__ hiB,
                            const float* __restrict__ ifB, const float* __restrict__ hfB,
                            const float* __restrict__ igB, const float* __restrict__ hgB,
                            const float* __restrict__ ioB, const float* __restrict__ hoB,
                            float* __restrict__ bias, unsigned short* __restrict__ hbuf0,
                            float* __restrict__ c_ws, unsigned int* __restrict__ bar) {
    int tid = blockIdx.x * 256 + threadIdx.x;   // grid 64 x 256 = 16384
    if (tid == 0) *bar = 0u;
    if (tid < 4096) {
        int g = tid >> 10, j = tid & 1023;
        const float* ib = (g == 0 ? iiB : g == 1 ? ifB : g == 2 ? igB : ioB);
        const float* hb = (g == 0 ? hiB : g == 1 ? hfB : g == 2 ? hgB : hoB);
        bias[tid] = ib[j] + hb[j];
    }
    for (int i = tid; i < 65536; i += 16384) { hbuf0[i] = 0; c_ws[i] = 0.f; }
}

// ---------------- weights -> bf16, gate-stacked n = g*1024 + j ----------------
__global__ void prep_weights(const float* __restrict__ iiW, const float* __restrict__ hiW,
                             const float* __restrict__ ifW, const float* __restrict__ hfW,
                             const float* __restrict__ igW, const float* __restrict__ hgW,
                             const float* __restrict__ ioW, const float* __restrict__ hoW,
                             unsigned short* __restrict__ Wx, unsigned short* __restrict__ Wh) {
    int n = blockIdx.x;               // 0..4095
    int g = n >> 10, j = n & 1023;
    const float* wx = (g == 0 ? iiW : g == 1 ? ifW : g == 2 ? igW : ioW) + (size_t)j * 1024;
    const float* wh = (g == 0 ? hiW : g == 1 ? hfW : g == 2 ? hgW : hoW) + (size_t)j * 1024;
    int k = threadIdx.x * 4;
    float4 a = *(const float4*)(wx + k);
    float4 b = *(const float4*)(wh + k);
    ushort4 ra = { f2bf(a.x), f2bf(a.y), f2bf(a.z), f2bf(a.w) };
    ushort4 rb = { f2bf(b.x), f2bf(b.y), f2bf(b.z), f2bf(b.w) };
    *(ushort4*)(Wx + (size_t)n * 1024 + k) = ra;
    *(ushort4*)(Wh + (size_t)n * 1024 + k) = rb;
}

// ---------------- Xproj GEMM: C[M][4096] = A[M][1024] @ Wx^T + bias ----------------
// 128x128 tile, BK=32, 4 waves each 64x64 (4x4 of 16x16x32 bf16 MFMA).
__global__ __launch_bounds__(256, 2) void xproj_gemm(const float* __restrict__ A,
                                                     const unsigned short* __restrict__ Wx,
                                                     const float* __restrict__ bias,
                                                     float* __restrict__ C) {
    __shared__ __align__(16) unsigned short Asm[128 * 32];  // 8KB, XOR-swizzled slots
    __shared__ __align__(16) unsigned short Bsm[128 * 32];  // 8KB
    int tid = threadIdx.x;
    int lane = tid & 63, wv = tid >> 6;
    int l15 = lane & 15, l4 = lane >> 4;
    int wrow = wv >> 1, wcol = wv & 1;
    int bn0 = blockIdx.x * 128, bm0 = blockIdx.y * 128;
    f32x4 acc[4][4] = {};

    for (int kk = 0; kk < 32; ++kk) {
        int k0 = kk * 32;
        __syncthreads();   // protect LDS from previous iteration's reads
        // stage A (fp32 -> bf16, swizzled ds_write): 512 tasks of 8 elems
#pragma unroll
        for (int it = 0; it < 2; ++it) {
            int tau = it * 256 + tid;
            int row = tau >> 2, slot = tau & 3;
            const float* src = A + (size_t)(bm0 + row) * 1024 + k0 + slot * 8;
            float4 x0 = *(const float4*)src;
            float4 x1 = *(const float4*)(src + 4);
            bf16x8 pk;
            pk[0] = (short)f2bf(x0.x); pk[1] = (short)f2bf(x0.y);
            pk[2] = (short)f2bf(x0.z); pk[3] = (short)f2bf(x0.w);
            pk[4] = (short)f2bf(x1.x); pk[5] = (short)f2bf(x1.y);
            pk[6] = (short)f2bf(x1.z); pk[7] = (short)f2bf(x1.w);
            int dslot = slot ^ (row & 3);
            *(bf16x8*)((char*)Asm + row * 64 + dslot * 16) = pk;
        }
        // stage B: global_load_lds, linear dest + inverse-swizzled source
#pragma unroll
        for (int it = 0; it < 2; ++it) {
            int tau = it * 256 + tid;
            int row = tau >> 2, slot = tau & 3;
            int sslot = slot ^ (row & 3);
            const unsigned short* src = Wx + (size_t)(bn0 + row) * 1024 + k0 + sslot * 8;
            char* ldsb = (char*)Bsm + it * 4096 + wv * 1024;   // wave-uniform base
            __builtin_amdgcn_global_load_lds((const __attribute__((address_space(1))) void*)src,
                                             (__attribute__((address_space(3))) void*)ldsb, 16, 0, 0);
        }
        __syncthreads();
        bf16x8 af[4], bfv[4];
#pragma unroll
        for (int i = 0; i < 4; ++i) {
            int rowa = wrow * 64 + i * 16 + l15;
            int sa = l4 ^ (rowa & 3);
            af[i] = *(const bf16x8*)((const char*)Asm + rowa * 64 + sa * 16);
            int rowb = wcol * 64 + i * 16 + l15;
            int sb = l4 ^ (rowb & 3);
            bfv[i] = *(const bf16x8*)((const char*)Bsm + rowb * 64 + sb * 16);
        }
#pragma unroll
        for (int i = 0; i < 4; ++i)
#pragma unroll
            for (int j = 0; j < 4; ++j)
                acc[i][j] = __builtin_amdgcn_mfma_f32_16x16x32_bf16(af[i], bfv[j], acc[i][j], 0, 0, 0);
    }
    // epilogue: C = acc + bias[n]
#pragma unroll
    for (int i = 0; i < 4; ++i) {
        int m = bm0 + wrow * 64 + i * 16 + l4 * 4;
#pragma unroll
        for (int j = 0; j < 4; ++j) {
            int n = bn0 + wcol * 64 + j * 16 + l15;
            float bs = bias[n];
#pragma unroll
            for (int r = 0; r < 4; ++r)
                C[(size_t)(m + r) * 4096 + n] = acc[i][j][r] + bs;
        }
    }
}

// ---------------- persistent recurrent kernel (one chunk of T steps) ----------------
// 128 WGs x 256 thr. WG (cg, mhalf): hidden units j0=16*cg..+16, all 4 gates,
// batch rows mhalf*32..+32. Waves K-split (256 each); weights in VGPRs.
__global__ __launch_bounds__(256, 1) void lstm_steps(const float* __restrict__ xproj,
                                                     unsigned short* __restrict__ hbuf,
                                                     float* __restrict__ c_ws,
                                                     const unsigned short* __restrict__ Wh,
                                                     unsigned int* __restrict__ bar,
                                                     float* __restrict__ out,
                                                     int t0, int T) {
    __shared__ __align__(16) unsigned char smem[65536];   // h stage (64KB) / red (32KB) overlaid
    int tid = threadIdx.x, lane = tid & 63, wv = tid >> 6;
    int l15 = lane & 15, l4 = lane >> 4;
    int wg = blockIdx.x;
    int mhalf = wg & 1;
    int cg = wg >> 1;
    int j0 = cg * 16;

    // load this wave's weight fragments: K slice [wv*256, wv*256+256), 4 gates x 16 units
    bf16x8 w[8][4];
#pragma unroll
    for (int ks = 0; ks < 8; ++ks)
#pragma unroll
        for (int g = 0; g < 4; ++g) {
            int n = g * 1024 + j0 + l15;
            int k = wv * 256 + ks * 32 + l4 * 8;
            w[ks][g] = *(const bf16x8*)(Wh + (size_t)n * 1024 + k);
        }

    // persistent c state: pairs p = 2*wv + pi, (m = p>>2, r = p&3)
    float c_reg[2];
#pragma unroll
    for (int pi = 0; pi < 2; ++pi) {
        int p = wv * 2 + pi, m = p >> 2, r = p & 3;
        int b = mhalf * 32 + m * 16 + l4 * 4 + r;
        c_reg[pi] = c_ws[(size_t)b * 1024 + j0 + l15];
    }

    for (int tl = 0; tl < T; ++tl) {
        int ts = t0 + tl;
        int par = ts & 1;
        const unsigned short* hb = hbuf + (size_t)par * 65536;
        // stage h[mhalf-half][1024] bf16 into LDS, XOR-swizzled via pre-swizzled global src
#pragma unroll
        for (int it = 0; it < 16; ++it) {
            int L = it * 4096 + tid * 16;
            int row = L >> 11;            // 0..31
            int x = L & 2047;
            int sx = x ^ ((row & 7) << 4);
            const unsigned short* src = hb + (size_t)(mhalf * 32 + row) * 1024 + (sx >> 1);
            __builtin_amdgcn_global_load_lds(
                (const __attribute__((address_space(1))) void*)src,
                (__attribute__((address_space(3))) void*)(smem + it * 4096 + wv * 1024), 16, 0, 0);
        }
        __syncthreads();

        f32x4 acc[2][4] = {};
#pragma unroll
        for (int ks = 0; ks < 8; ++ks) {
#pragma unroll
            for (int m = 0; m < 2; ++m) {
                int row = m * 16 + l15;
                int xb = wv * 512 + ks * 64 + l4 * 16;
                bf16x8 a = *(const bf16x8*)(smem + row * 2048 + (xb ^ ((row & 7) << 4)));
#pragma unroll
                for (int g = 0; g < 4; ++g)
                    acc[m][g] = __builtin_amdgcn_mfma_f32_16x16x32_bf16(a, w[ks][g], acc[m][g], 0, 0, 0);
            }
        }
        __syncthreads();
        // cross-wave K reduction in LDS: red[wv][32][64] fp32 (32KB)
        float* red = (float*)smem;
#pragma unroll
        for (int m = 0; m < 2; ++m)
#pragma unroll
            for (int g = 0; g < 4; ++g)
#pragma unroll
                for (int r = 0; r < 4; ++r)
                    red[(wv * 32 + m * 16 + g * 4 + r) * 64 + lane] = acc[m][g][r];
        __syncthreads();

        // pointwise: wave wv handles pairs 2wv, 2wv+1
#pragma unroll
        for (int pi = 0; pi < 2; ++pi) {
            int p = wv * 2 + pi, m = p >> 2, r = p & 3;
            int b = mhalf * 32 + m * 16 + l4 * 4 + r;
            int j = j0 + l15;
            float pre[4];
#pragma unroll
            for (int g = 0; g < 4; ++g) {
                int s = m * 16 + g * 4 + r;
                float v = red[s * 64 + lane] + red[(32 + s) * 64 + lane] +
                          red[(64 + s) * 64 + lane] + red[(96 + s) * 64 + lane];
                pre[g] = v + xproj[(size_t)(tl * 64 + b) * 4096 + g * 1024 + j];
            }
            float I = 1.f / (1.f + __expf(-pre[0]));
            float F = 1.f / (1.f + __expf(-pre[1]));
            float G = tanhf(pre[2]);
            float O = 1.f / (1.f + __expf(-pre[3]));
            float c = F * c_reg[pi] + I * G;
            c_reg[pi] = c;
            float y = O * tanhf(c);
            out[(size_t)(ts * 64 + b) * 1024 + j] = y;
            hbuf[(size_t)(par ^ 1) * 65536 + (size_t)b * 1024 + j] = f2bf(y);
            if (ts == 1023) {
                out[67108864u + (size_t)b * 1024 + j] = y;            // hT
                out[67108864u + 65536u + (size_t)b * 1024 + j] = c;   // cT
            }
        }
        // grid barrier (device-scope, monotonic counter)
        __syncthreads();
        if (tid == 0) {
            __builtin_amdgcn_fence(__ATOMIC_RELEASE, "agent");
            __hip_atomic_fetch_add(bar, 1u, __ATOMIC_RELAXED, __HIP_MEMORY_SCOPE_AGENT);
            unsigned target = (unsigned)(ts + 1) * NWG;
            while (__hip_atomic_load(bar, __ATOMIC_RELAXED, __HIP_MEMORY_SCOPE_AGENT) < target)
                __builtin_amdgcn_s_sleep(2);
        }
        __syncthreads();
        __builtin_amdgcn_fence(__ATOMIC_ACQUIRE, "agent");
    }
    // persist c across chunk launches
#pragma unroll
    for (int pi = 0; pi < 2; ++pi) {
        int p = wv * 2 + pi, m = p >> 2, r = p & 3;
        int b = mhalf * 32 + m * 16 + l4 * 4 + r;
        c_ws[(size_t)b * 1024 + j0 + l15] = c_reg[pi];
    }
}

extern "C" void kernel_launch(void* const* d_in, const int* in_sizes, int n_in,
                              void* d_out, int out_size, void* d_ws, size_t ws_size,
                              hipStream_t stream) {
    (void)in_sizes; (void)n_in; (void)out_size;
    const float* Xt = (const float*)d_in[0];
    const float* W[8]; for (int i = 0; i < 8; ++i) W[i] = (const float*)d_in[1 + i];
    const float* Bv[8]; for (int i = 0; i < 8; ++i) Bv[i] = (const float*)d_in[9 + i];
    float* out = (float*)d_out;
    uint8_t* ws = (uint8_t*)d_ws;

    unsigned int*  bar   = (unsigned int*)(ws + 0);
    float*         bias  = (float*)(ws + 256);
    unsigned short* hbuf = (unsigned short*)(ws + 16640);     // [2][64][1024] bf16
    float*         c_ws  = (float*)(ws + 278784);             // [64][1024] fp32
    unsigned short* Wx   = (unsigned short*)(ws + 540928);    // [4096][1024] bf16
    unsigned short* Wh   = (unsigned short*)(ws + 8929536);   // [4096][1024] bf16
    float*         xproj = (float*)(ws + 17318144);           // [T*64][4096] fp32

    size_t avail = ws_size > 17318144 ? ws_size - 17318144 : 0;
    int T = 4;
    for (int t = 1024; t >= 4; t >>= 1)
        if ((size_t)t * 1048576ull <= avail) { T = t; break; }

    init_kernel<<<64, 256, 0, stream>>>(Bv[0], Bv[1], Bv[2], Bv[3], Bv[4], Bv[5], Bv[6], Bv[7],
                                        bias, hbuf, c_ws, bar);
    prep_weights<<<4096, 256, 0, stream>>>(W[0], W[1], W[2], W[3], W[4], W[5], W[6], W[7], Wx, Wh);

    int nch = 1024 / T;
    for (int c = 0; c < nch; ++c) {
        xproj_gemm<<<dim3(32, T / 2), 256, 0, stream>>>(Xt + (size_t)c * T * 65536, Wx, bias, xproj);
        lstm_steps<<<NWG, 256, 0, stream>>>(xproj, hbuf, c_ws, Wh, bar, out, c * T, T);
    }
}

// Round 3
// 10001.598 us; speedup vs baseline: 1.5345x; 1.5345x over previous
//
#include <hip/hip_runtime.h>
#include <hip/hip_bf16.h>
#include <stdint.h>

// LSTM: S=1024, B=64, D=1024, H=1024. fp32 in/out, bf16 MFMA internally.
// out = [Yt (S*B*H) | hT (B*H) | cT (B*H)] fp32.
// Recurrence: 128 persistent WGs, Wh in VGPRs, h exchanged via agent-scope
// (L2-bypassing) atomics -- NO cache-wide fences in the per-step loop.

#define NWG 128

typedef __attribute__((ext_vector_type(8))) short bf16x8;
typedef __attribute__((ext_vector_type(4))) float f32x4;

__device__ __forceinline__ unsigned short f2bf(float f) {
    unsigned u = __builtin_bit_cast(unsigned, f);
    return (unsigned short)((u + 0x7fffu + ((u >> 16) & 1u)) >> 16);
}

// ---------------- init: bias fusion + state zeroing ----------------
__global__ void init_kernel(const float* __restrict__ iiB, const float* __restrict__ hiB,
                            const float* __restrict__ ifB, const float* __restrict__ hfB,
                            const float* __restrict__ igB, const float* __restrict__ hgB,
                            const float* __restrict__ ioB, const float* __restrict__ hoB,
                            float* __restrict__ bias, unsigned short* __restrict__ hbuf0,
                            float* __restrict__ c_ws, unsigned int* __restrict__ bar) {
    int tid = blockIdx.x * 256 + threadIdx.x;   // grid 64 x 256 = 16384
    if (tid == 0) *bar = 0u;
    if (tid < 4096) {
        int g = tid >> 10, j = tid & 1023;
        const float* ib = (g == 0 ? iiB : g == 1 ? ifB : g == 2 ? igB : ioB);
        const float* hb = (g == 0 ? hiB : g == 1 ? hfB : g == 2 ? hgB : hoB);
        bias[tid] = ib[j] + hb[j];
    }
    for (int i = tid; i < 65536; i += 16384) {
        // h0 = 0, published the same way the step loop publishes (agent scope)
        __hip_atomic_store(hbuf0 + i, (unsigned short)0, __ATOMIC_RELAXED, __HIP_MEMORY_SCOPE_AGENT);
        c_ws[i] = 0.f;
    }
}

// ---------------- weights -> bf16, gate-stacked n = g*1024 + j ----------------
__global__ void prep_weights(const float* __restrict__ iiW, const float* __restrict__ hiW,
                             const float* __restrict__ ifW, const float* __restrict__ hfW,
                             const float* __restrict__ igW, const float* __restrict__ hgW,
                             const float* __restrict__ ioW, const float* __restrict__ hoW,
                             unsigned short* __restrict__ Wx, unsigned short* __restrict__ Wh) {
    int n = blockIdx.x;               // 0..4095
    int g = n >> 10, j = n & 1023;
    const float* wx = (g == 0 ? iiW : g == 1 ? ifW : g == 2 ? igW : ioW) + (size_t)j * 1024;
    const float* wh = (g == 0 ? hiW : g == 1 ? hfW : g == 2 ? hgW : hoW) + (size_t)j * 1024;
    int k = threadIdx.x * 4;
    float4 a = *(const float4*)(wx + k);
    float4 b = *(const float4*)(wh + k);
    ushort4 ra = { f2bf(a.x), f2bf(a.y), f2bf(a.z), f2bf(a.w) };
    ushort4 rb = { f2bf(b.x), f2bf(b.y), f2bf(b.z), f2bf(b.w) };
    *(ushort4*)(Wx + (size_t)n * 1024 + k) = ra;
    *(ushort4*)(Wh + (size_t)n * 1024 + k) = rb;
}

// ---------------- Xproj GEMM: C[M][4096] = A[M][1024] @ Wx^T + bias ----------------
// 128x128 tile, BK=32, 4 waves each 64x64 (4x4 of 16x16x32 bf16 MFMA).
__global__ __launch_bounds__(256, 2) void xproj_gemm(const float* __restrict__ A,
                                                     const unsigned short* __restrict__ Wx,
                                                     const float* __restrict__ bias,
                                                     float* __restrict__ C) {
    __shared__ __align__(16) unsigned short Asm[128 * 32];  // 8KB, XOR-swizzled slots
    __shared__ __align__(16) unsigned short Bsm[128 * 32];  // 8KB
    int tid = threadIdx.x;
    int lane = tid & 63, wv = tid >> 6;
    int l15 = lane & 15, l4 = lane >> 4;
    int wrow = wv >> 1, wcol = wv & 1;
    int bn0 = blockIdx.x * 128, bm0 = blockIdx.y * 128;
    f32x4 acc[4][4] = {};

    for (int kk = 0; kk < 32; ++kk) {
        int k0 = kk * 32;
        __syncthreads();   // protect LDS from previous iteration's reads
        // stage A (fp32 -> bf16, swizzled ds_write): 512 tasks of 8 elems
#pragma unroll
        for (int it = 0; it < 2; ++it) {
            int tau = it * 256 + tid;
            int row = tau >> 2, slot = tau & 3;
            const float* src = A + (size_t)(bm0 + row) * 1024 + k0 + slot * 8;
            float4 x0 = *(const float4*)src;
            float4 x1 = *(const float4*)(src + 4);
            bf16x8 pk;
            pk[0] = (short)f2bf(x0.x); pk[1] = (short)f2bf(x0.y);
            pk[2] = (short)f2bf(x0.z); pk[3] = (short)f2bf(x0.w);
            pk[4] = (short)f2bf(x1.x); pk[5] = (short)f2bf(x1.y);
            pk[6] = (short)f2bf(x1.z); pk[7] = (short)f2bf(x1.w);
            int dslot = slot ^ (row & 3);
            *(bf16x8*)((char*)Asm + row * 64 + dslot * 16) = pk;
        }
        // stage B: global_load_lds, linear dest + inverse-swizzled source
#pragma unroll
        for (int it = 0; it < 2; ++it) {
            int tau = it * 256 + tid;
            int row = tau >> 2, slot = tau & 3;
            int sslot = slot ^ (row & 3);
            const unsigned short* src = Wx + (size_t)(bn0 + row) * 1024 + k0 + sslot * 8;
            char* ldsb = (char*)Bsm + it * 4096 + wv * 1024;   // wave-uniform base
            __builtin_amdgcn_global_load_lds((const __attribute__((address_space(1))) void*)src,
                                             (__attribute__((address_space(3))) void*)ldsb, 16, 0, 0);
        }
        __syncthreads();
        bf16x8 af[4], bfv[4];
#pragma unroll
        for (int i = 0; i < 4; ++i) {
            int rowa = wrow * 64 + i * 16 + l15;
            int sa = l4 ^ (rowa & 3);
            af[i] = *(const bf16x8*)((const char*)Asm + rowa * 64 + sa * 16);
            int rowb = wcol * 64 + i * 16 + l15;
            int sb = l4 ^ (rowb & 3);
            bfv[i] = *(const bf16x8*)((const char*)Bsm + rowb * 64 + sb * 16);
        }
#pragma unroll
        for (int i = 0; i < 4; ++i)
#pragma unroll
            for (int j = 0; j < 4; ++j)
                acc[i][j] = __builtin_amdgcn_mfma_f32_16x16x32_bf16(af[i], bfv[j], acc[i][j], 0, 0, 0);
    }
    // epilogue: C = acc + bias[n]
#pragma unroll
    for (int i = 0; i < 4; ++i) {
        int m = bm0 + wrow * 64 + i * 16 + l4 * 4;
#pragma unroll
        for (int j = 0; j < 4; ++j) {
            int n = bn0 + wcol * 64 + j * 16 + l15;
            float bs = bias[n];
#pragma unroll
            for (int r = 0; r < 4; ++r)
                C[(size_t)(m + r) * 4096 + n] = acc[i][j][r] + bs;
        }
    }
}

// ---------------- persistent recurrent kernel (one chunk of T steps) ----------------
// 128 WGs x 256 thr. WG (cg, mhalf): hidden units j0=16*cg..+16, all 4 gates,
// batch rows mhalf*32..+32. Waves K-split (256 each); weights in VGPRs.
// h exchange: agent-scope relaxed atomics (L2-bypass), no fences.
__global__ __launch_bounds__(256, 1) void lstm_steps(const float* __restrict__ xproj,
                                                     unsigned short* __restrict__ hbuf,
                                                     float* __restrict__ c_ws,
                                                     const unsigned short* __restrict__ Wh,
                                                     unsigned int* __restrict__ bar,
                                                     float* __restrict__ out,
                                                     int t0, int T) {
    __shared__ float red[8192];   // 32KB: [wv][32][64]
    int tid = threadIdx.x, lane = tid & 63, wv = tid >> 6;
    int l15 = lane & 15, l4 = lane >> 4;
    int wg = blockIdx.x;
    int mhalf = wg & 1;
    int cg = wg >> 1;
    int j0 = cg * 16;

    // this wave's weight fragments: K slice [wv*256, +256), 4 gates x 16 units
    bf16x8 w[8][4];
#pragma unroll
    for (int ks = 0; ks < 8; ++ks)
#pragma unroll
        for (int g = 0; g < 4; ++g) {
            int n = g * 1024 + j0 + l15;
            int k = wv * 256 + ks * 32 + l4 * 8;
            w[ks][g] = *(const bf16x8*)(Wh + (size_t)n * 1024 + k);
        }

    // persistent c state: pairs p = 2*wv + pi, (m = p>>2, r = p&3)
    float c_reg[2];
#pragma unroll
    for (int pi = 0; pi < 2; ++pi) {
        int p = wv * 2 + pi, m = p >> 2, r = p & 3;
        int b = mhalf * 32 + m * 16 + l4 * 4 + r;
        c_reg[pi] = c_ws[(size_t)b * 1024 + j0 + l15];
    }

    for (int tl = 0; tl < T; ++tl) {
        int ts = t0 + tl;
        int par = ts & 1;
        const unsigned short* hb = hbuf + (size_t)par * 65536;

        // A-fragments straight from global (agent-scope loads bypass stale L2).
        // frag (m, ks): rows m*16+l15 of this mhalf-half, K = wv*256+ks*32+l4*8.
        bf16x8 af[2][8];
#pragma unroll
        for (int m = 0; m < 2; ++m) {
            int row = mhalf * 32 + m * 16 + l15;
            const unsigned short* rp = hb + (size_t)row * 1024 + wv * 256 + l4 * 8;
#pragma unroll
            for (int ks = 0; ks < 8; ++ks) {
                unsigned long long* p = (unsigned long long*)(rp + ks * 32);
                union { unsigned long long q[2]; bf16x8 v; } u;
                u.q[0] = __hip_atomic_load(p,     __ATOMIC_RELAXED, __HIP_MEMORY_SCOPE_AGENT);
                u.q[1] = __hip_atomic_load(p + 1, __ATOMIC_RELAXED, __HIP_MEMORY_SCOPE_AGENT);
                af[m][ks] = u.v;
            }
        }

        f32x4 acc[2][4] = {};
#pragma unroll
        for (int ks = 0; ks < 8; ++ks)
#pragma unroll
            for (int m = 0; m < 2; ++m)
#pragma unroll
                for (int g = 0; g < 4; ++g)
                    acc[m][g] = __builtin_amdgcn_mfma_f32_16x16x32_bf16(af[m][ks], w[ks][g], acc[m][g], 0, 0, 0);

        // cross-wave K reduction in LDS
#pragma unroll
        for (int m = 0; m < 2; ++m)
#pragma unroll
            for (int g = 0; g < 4; ++g)
#pragma unroll
                for (int r = 0; r < 4; ++r)
                    red[(wv * 32 + m * 16 + g * 4 + r) * 64 + lane] = acc[m][g][r];
        __syncthreads();

        // pointwise: wave wv handles pairs 2wv, 2wv+1
#pragma unroll
        for (int pi = 0; pi < 2; ++pi) {
            int p = wv * 2 + pi, m = p >> 2, r = p & 3;
            int b = mhalf * 32 + m * 16 + l4 * 4 + r;
            int j = j0 + l15;
            float pre[4];
#pragma unroll
            for (int g = 0; g < 4; ++g) {
                int s = m * 16 + g * 4 + r;
                float v = red[s * 64 + lane] + red[(32 + s) * 64 + lane] +
                          red[(64 + s) * 64 + lane] + red[(96 + s) * 64 + lane];
                pre[g] = v + xproj[(size_t)(tl * 64 + b) * 4096 + g * 1024 + j];
            }
            float I = 1.f / (1.f + __expf(-pre[0]));
            float F = 1.f / (1.f + __expf(-pre[1]));
            float G = tanhf(pre[2]);
            float O = 1.f / (1.f + __expf(-pre[3]));
            float c = F * c_reg[pi] + I * G;
            c_reg[pi] = c;
            float y = O * tanhf(c);
            out[(size_t)(ts * 64 + b) * 1024 + j] = y;
            __hip_atomic_store(hbuf + (size_t)(par ^ 1) * 65536 + (size_t)b * 1024 + j,
                               f2bf(y), __ATOMIC_RELAXED, __HIP_MEMORY_SCOPE_AGENT);
            if (ts == 1023) {
                out[67108864u + (size_t)b * 1024 + j] = y;            // hT
                out[67108864u + 65536u + (size_t)b * 1024 + j] = c;   // cT
            }
        }
        // grid barrier: __syncthreads drains each wave's vmcnt (h stores acked
        // at the coherence point) before tid0 increments the counter.
        __syncthreads();
        if (tid == 0) {
            __hip_atomic_fetch_add(bar, 1u, __ATOMIC_RELAXED, __HIP_MEMORY_SCOPE_AGENT);
            unsigned target = (unsigned)(ts + 1) * NWG;
            while (__hip_atomic_load(bar, __ATOMIC_RELAXED, __HIP_MEMORY_SCOPE_AGENT) < target)
                __builtin_amdgcn_s_sleep(2);
        }
        __syncthreads();
    }
    // persist c across chunk launches
#pragma unroll
    for (int pi = 0; pi < 2; ++pi) {
        int p = wv * 2 + pi, m = p >> 2, r = p & 3;
        int b = mhalf * 32 + m * 16 + l4 * 4 + r;
        c_ws[(size_t)b * 1024 + j0 + l15] = c_reg[pi];
    }
}

extern "C" void kernel_launch(void* const* d_in, const int* in_sizes, int n_in,
                              void* d_out, int out_size, void* d_ws, size_t ws_size,
                              hipStream_t stream) {
    (void)in_sizes; (void)n_in; (void)out_size;
    const float* Xt = (const float*)d_in[0];
    const float* W[8]; for (int i = 0; i < 8; ++i) W[i] = (const float*)d_in[1 + i];
    const float* Bv[8]; for (int i = 0; i < 8; ++i) Bv[i] = (const float*)d_in[9 + i];
    float* out = (float*)d_out;
    uint8_t* ws = (uint8_t*)d_ws;

    unsigned int*  bar   = (unsigned int*)(ws + 0);
    float*         bias  = (float*)(ws + 256);
    unsigned short* hbuf = (unsigned short*)(ws + 16640);     // [2][64][1024] bf16
    float*         c_ws  = (float*)(ws + 278784);             // [64][1024] fp32
    unsigned short* Wx   = (unsigned short*)(ws + 540928);    // [4096][1024] bf16
    unsigned short* Wh   = (unsigned short*)(ws + 8929536);   // [4096][1024] bf16
    float*         xproj = (float*)(ws + 17318144);           // [T*64][4096] fp32

    size_t avail = ws_size > 17318144 ? ws_size - 17318144 : 0;
    int T = 4;
    for (int t = 1024; t >= 4; t >>= 1)
        if ((size_t)t * 1048576ull <= avail) { T = t; break; }

    init_kernel<<<64, 256, 0, stream>>>(Bv[0], Bv[1], Bv[2], Bv[3], Bv[4], Bv[5], Bv[6], Bv[7],
                                        bias, hbuf, c_ws, bar);
    prep_weights<<<4096, 256, 0, stream>>>(W[0], W[1], W[2], W[3], W[4], W[5], W[6], W[7], Wx, Wh);

    int nch = 1024 / T;
    for (int c = 0; c < nch; ++c) {
        xproj_gemm<<<dim3(32, T / 2), 256, 0, stream>>>(Xt + (size_t)c * T * 65536, Wx, bias, xproj);
        lstm_steps<<<NWG, 256, 0, stream>>>(xproj, hbuf, c_ws, Wh, bar, out, c * T, T);
    }
}

// Round 4
// 7792.014 us; speedup vs baseline: 1.9696x; 1.2836x over previous
//
#include <hip/hip_runtime.h>
#include <hip/hip_bf16.h>
#include <stdint.h>

// LSTM: S=1024, B=64, D=1024, H=1024. fp32 in/out, bf16 MFMA internally.
// out = [Yt (S*B*H) | hT (B*H) | cT (B*H)] fp32.
// Recurrence: 128 persistent WGs, Wh in VGPRs, h exchanged via agent-scope
// (L2-bypassing) atomics. Per-mhalf split barrier; xproj prefetched; out
// stores deferred past the barrier so their HBM acks leave the critical path.

#define NWG 128

typedef __attribute__((ext_vector_type(8))) short bf16x8;
typedef __attribute__((ext_vector_type(4))) float f32x4;

__device__ __forceinline__ unsigned short f2bf(float f) {
    unsigned u = __builtin_bit_cast(unsigned, f);
    return (unsigned short)((u + 0x7fffu + ((u >> 16) & 1u)) >> 16);
}

// ---------------- init: bias fusion + state zeroing ----------------
__global__ void init_kernel(const float* __restrict__ iiB, const float* __restrict__ hiB,
                            const float* __restrict__ ifB, const float* __restrict__ hfB,
                            const float* __restrict__ igB, const float* __restrict__ hgB,
                            const float* __restrict__ ioB, const float* __restrict__ hoB,
                            float* __restrict__ bias, unsigned short* __restrict__ hbuf0,
                            float* __restrict__ c_ws, unsigned int* __restrict__ bar) {
    int tid = blockIdx.x * 256 + threadIdx.x;   // grid 64 x 256 = 16384
    if (tid < 64) bar[tid] = 0u;                // counters at bar[0], bar[32]
    if (tid < 4096) {
        int g = tid >> 10, j = tid & 1023;
        const float* ib = (g == 0 ? iiB : g == 1 ? ifB : g == 2 ? igB : ioB);
        const float* hb = (g == 0 ? hiB : g == 1 ? hfB : g == 2 ? hgB : hoB);
        bias[tid] = ib[j] + hb[j];
    }
    for (int i = tid; i < 65536; i += 16384) {
        __hip_atomic_store(hbuf0 + i, (unsigned short)0, __ATOMIC_RELAXED, __HIP_MEMORY_SCOPE_AGENT);
        c_ws[i] = 0.f;
    }
}

// ---------------- weights -> bf16, gate-stacked n = g*1024 + j ----------------
__global__ void prep_weights(const float* __restrict__ iiW, const float* __restrict__ hiW,
                             const float* __restrict__ ifW, const float* __restrict__ hfW,
                             const float* __restrict__ igW, const float* __restrict__ hgW,
                             const float* __restrict__ ioW, const float* __restrict__ hoW,
                             unsigned short* __restrict__ Wx, unsigned short* __restrict__ Wh) {
    int n = blockIdx.x;               // 0..4095
    int g = n >> 10, j = n & 1023;
    const float* wx = (g == 0 ? iiW : g == 1 ? ifW : g == 2 ? igW : ioW) + (size_t)j * 1024;
    const float* wh = (g == 0 ? hiW : g == 1 ? hfW : g == 2 ? hgW : hoW) + (size_t)j * 1024;
    int k = threadIdx.x * 4;
    float4 a = *(const float4*)(wx + k);
    float4 b = *(const float4*)(wh + k);
    ushort4 ra = { f2bf(a.x), f2bf(a.y), f2bf(a.z), f2bf(a.w) };
    ushort4 rb = { f2bf(b.x), f2bf(b.y), f2bf(b.z), f2bf(b.w) };
    *(ushort4*)(Wx + (size_t)n * 1024 + k) = ra;
    *(ushort4*)(Wh + (size_t)n * 1024 + k) = rb;
}

// ---------------- Xproj GEMM: C[M][4096] = A[M][1024] @ Wx^T + bias ----------------
// 128x128 tile, BK=32, 4 waves each 64x64 (4x4 of 16x16x32 bf16 MFMA).
__global__ __launch_bounds__(256, 2) void xproj_gemm(const float* __restrict__ A,
                                                     const unsigned short* __restrict__ Wx,
                                                     const float* __restrict__ bias,
                                                     float* __restrict__ C) {
    __shared__ __align__(16) unsigned short Asm[128 * 32];  // 8KB, XOR-swizzled slots
    __shared__ __align__(16) unsigned short Bsm[128 * 32];  // 8KB
    int tid = threadIdx.x;
    int lane = tid & 63, wv = tid >> 6;
    int l15 = lane & 15, l4 = lane >> 4;
    int wrow = wv >> 1, wcol = wv & 1;
    int bn0 = blockIdx.x * 128, bm0 = blockIdx.y * 128;
    f32x4 acc[4][4] = {};

    for (int kk = 0; kk < 32; ++kk) {
        int k0 = kk * 32;
        __syncthreads();   // protect LDS from previous iteration's reads
        // stage A (fp32 -> bf16, swizzled ds_write): 512 tasks of 8 elems
#pragma unroll
        for (int it = 0; it < 2; ++it) {
            int tau = it * 256 + tid;
            int row = tau >> 2, slot = tau & 3;
            const float* src = A + (size_t)(bm0 + row) * 1024 + k0 + slot * 8;
            float4 x0 = *(const float4*)src;
            float4 x1 = *(const float4*)(src + 4);
            bf16x8 pk;
            pk[0] = (short)f2bf(x0.x); pk[1] = (short)f2bf(x0.y);
            pk[2] = (short)f2bf(x0.z); pk[3] = (short)f2bf(x0.w);
            pk[4] = (short)f2bf(x1.x); pk[5] = (short)f2bf(x1.y);
            pk[6] = (short)f2bf(x1.z); pk[7] = (short)f2bf(x1.w);
            int dslot = slot ^ (row & 3);
            *(bf16x8*)((char*)Asm + row * 64 + dslot * 16) = pk;
        }
        // stage B: global_load_lds, linear dest + inverse-swizzled source
#pragma unroll
        for (int it = 0; it < 2; ++it) {
            int tau = it * 256 + tid;
            int row = tau >> 2, slot = tau & 3;
            int sslot = slot ^ (row & 3);
            const unsigned short* src = Wx + (size_t)(bn0 + row) * 1024 + k0 + sslot * 8;
            char* ldsb = (char*)Bsm + it * 4096 + wv * 1024;   // wave-uniform base
            __builtin_amdgcn_global_load_lds((const __attribute__((address_space(1))) void*)src,
                                             (__attribute__((address_space(3))) void*)ldsb, 16, 0, 0);
        }
        __syncthreads();
        bf16x8 af[4], bfv[4];
#pragma unroll
        for (int i = 0; i < 4; ++i) {
            int rowa = wrow * 64 + i * 16 + l15;
            int sa = l4 ^ (rowa & 3);
            af[i] = *(const bf16x8*)((const char*)Asm + rowa * 64 + sa * 16);
            int rowb = wcol * 64 + i * 16 + l15;
            int sb = l4 ^ (rowb & 3);
            bfv[i] = *(const bf16x8*)((const char*)Bsm + rowb * 64 + sb * 16);
        }
#pragma unroll
        for (int i = 0; i < 4; ++i)
#pragma unroll
            for (int j = 0; j < 4; ++j)
                acc[i][j] = __builtin_amdgcn_mfma_f32_16x16x32_bf16(af[i], bfv[j], acc[i][j], 0, 0, 0);
    }
    // epilogue: C = acc + bias[n]
#pragma unroll
    for (int i = 0; i < 4; ++i) {
        int m = bm0 + wrow * 64 + i * 16 + l4 * 4;
#pragma unroll
        for (int j = 0; j < 4; ++j) {
            int n = bn0 + wcol * 64 + j * 16 + l15;
            float bs = bias[n];
#pragma unroll
            for (int r = 0; r < 4; ++r)
                C[(size_t)(m + r) * 4096 + n] = acc[i][j][r] + bs;
        }
    }
}

// ---------------- persistent recurrent kernel (one chunk of T steps) ----------------
// 128 WGs x 256 thr. WG (cg, mhalf): hidden units j0=16*cg..+16, all 4 gates,
// batch rows mhalf*32..+32. Waves K-split (256 each); weights in VGPRs.
// Barrier split per mhalf (the two halves are fully decoupled in h).
__global__ __launch_bounds__(256, 1) void lstm_steps(const float* __restrict__ xproj,
                                                     unsigned short* __restrict__ hbuf,
                                                     float* __restrict__ c_ws,
                                                     const unsigned short* __restrict__ Wh,
                                                     unsigned int* __restrict__ bar,
                                                     float* __restrict__ out,
                                                     int t0, int T) {
    __shared__ float red[8192];   // 32KB: [wv][32][64]
    int tid = threadIdx.x, lane = tid & 63, wv = tid >> 6;
    int l15 = lane & 15, l4 = lane >> 4;
    int wg = blockIdx.x;
    int mhalf = wg & 1;
    int cg = wg >> 1;
    int j0 = cg * 16;
    unsigned int* mybar = bar + mhalf * 32;   // 128B apart -> separate lines

    // this wave's weight fragments: K slice [wv*256, +256), 4 gates x 16 units
    bf16x8 w[8][4];
#pragma unroll
    for (int ks = 0; ks < 8; ++ks)
#pragma unroll
        for (int g = 0; g < 4; ++g) {
            int n = g * 1024 + j0 + l15;
            int k = wv * 256 + ks * 32 + l4 * 8;
            w[ks][g] = *(const bf16x8*)(Wh + (size_t)n * 1024 + k);
        }

    // persistent c state: pairs p = 2*wv + pi, (m = p>>2, r = p&3)
    float c_reg[2];
#pragma unroll
    for (int pi = 0; pi < 2; ++pi) {
        int p = wv * 2 + pi, m = p >> 2, r = p & 3;
        int b = mhalf * 32 + m * 16 + l4 * 4 + r;
        c_reg[pi] = c_ws[(size_t)b * 1024 + j0 + l15];
    }

    for (int tl = 0; tl < T; ++tl) {
        int ts = t0 + tl;
        int par = ts & 1;
        const unsigned short* hb = hbuf + (size_t)par * 65536;

        // ---- xproj prefetch (independent of h; overlaps h load + MFMA) ----
        float xp[2][4];
#pragma unroll
        for (int pi = 0; pi < 2; ++pi) {
            int p = wv * 2 + pi, m = p >> 2, r = p & 3;
            int b = mhalf * 32 + m * 16 + l4 * 4 + r;
#pragma unroll
            for (int g = 0; g < 4; ++g)
                xp[pi][g] = xproj[(size_t)(tl * 64 + b) * 4096 + g * 1024 + j0 + l15];
        }

        // ---- h fragments straight from global (agent loads bypass stale L2) ----
        bf16x8 af[2][8];
#pragma unroll
        for (int m = 0; m < 2; ++m) {
            int row = mhalf * 32 + m * 16 + l15;
            const unsigned short* rp = hb + (size_t)row * 1024 + wv * 256 + l4 * 8;
#pragma unroll
            for (int ks = 0; ks < 8; ++ks) {
                unsigned long long* p = (unsigned long long*)(rp + ks * 32);
                union { unsigned long long q[2]; bf16x8 v; } u;
                u.q[0] = __hip_atomic_load(p,     __ATOMIC_RELAXED, __HIP_MEMORY_SCOPE_AGENT);
                u.q[1] = __hip_atomic_load(p + 1, __ATOMIC_RELAXED, __HIP_MEMORY_SCOPE_AGENT);
                af[m][ks] = u.v;
            }
        }

        f32x4 acc[2][4] = {};
#pragma unroll
        for (int ks = 0; ks < 8; ++ks)
#pragma unroll
            for (int m = 0; m < 2; ++m)
#pragma unroll
                for (int g = 0; g < 4; ++g)
                    acc[m][g] = __builtin_amdgcn_mfma_f32_16x16x32_bf16(af[m][ks], w[ks][g], acc[m][g], 0, 0, 0);

        // cross-wave K reduction in LDS
#pragma unroll
        for (int m = 0; m < 2; ++m)
#pragma unroll
            for (int g = 0; g < 4; ++g)
#pragma unroll
                for (int r = 0; r < 4; ++r)
                    red[(wv * 32 + m * 16 + g * 4 + r) * 64 + lane] = acc[m][g][r];
        __syncthreads();

        // pointwise: wave wv handles pairs 2wv, 2wv+1; publish h (L3-ack'd),
        // keep y/c in regs for post-barrier HBM stores.
        float yv[2];
#pragma unroll
        for (int pi = 0; pi < 2; ++pi) {
            int p = wv * 2 + pi, m = p >> 2, r = p & 3;
            int b = mhalf * 32 + m * 16 + l4 * 4 + r;
            int j = j0 + l15;
            float pre[4];
#pragma unroll
            for (int g = 0; g < 4; ++g) {
                int s = m * 16 + g * 4 + r;
                pre[g] = red[s * 64 + lane] + red[(32 + s) * 64 + lane] +
                         red[(64 + s) * 64 + lane] + red[(96 + s) * 64 + lane] + xp[pi][g];
            }
            float I = 1.f / (1.f + __expf(-pre[0]));
            float F = 1.f / (1.f + __expf(-pre[1]));
            float G = tanhf(pre[2]);
            float O = 1.f / (1.f + __expf(-pre[3]));
            float c = F * c_reg[pi] + I * G;
            c_reg[pi] = c;
            float y = O * tanhf(c);
            yv[pi] = y;
            __hip_atomic_store(hbuf + (size_t)(par ^ 1) * 65536 + (size_t)b * 1024 + j,
                               f2bf(y), __ATOMIC_RELAXED, __HIP_MEMORY_SCOPE_AGENT);
        }

        // grid barrier (per mhalf): __syncthreads drains this WG's h stores
        // (L3 ack) before tid0 increments; out stores are NOT yet issued.
        __syncthreads();
        if (tid == 0) {
            __hip_atomic_fetch_add(mybar, 1u, __ATOMIC_RELAXED, __HIP_MEMORY_SCOPE_AGENT);
            unsigned target = (unsigned)(ts + 1) * 64u;
            while (__hip_atomic_load(mybar, __ATOMIC_RELAXED, __HIP_MEMORY_SCOPE_AGENT) < target)
                __builtin_amdgcn_s_sleep(1);
        }
        __syncthreads();

        // deferred HBM stores: overlap with next step's h load + MFMA; the
        // next LDS-reduce __syncthreads drains them off the critical path.
#pragma unroll
        for (int pi = 0; pi < 2; ++pi) {
            int p = wv * 2 + pi, m = p >> 2, r = p & 3;
            int b = mhalf * 32 + m * 16 + l4 * 4 + r;
            int j = j0 + l15;
            out[(size_t)(ts * 64 + b) * 1024 + j] = yv[pi];
            if (ts == 1023) {
                out[67108864u + (size_t)b * 1024 + j] = yv[pi];           // hT
                out[67108864u + 65536u + (size_t)b * 1024 + j] = c_reg[pi]; // cT
            }
        }
    }
    // persist c across chunk launches
#pragma unroll
    for (int pi = 0; pi < 2; ++pi) {
        int p = wv * 2 + pi, m = p >> 2, r = p & 3;
        int b = mhalf * 32 + m * 16 + l4 * 4 + r;
        c_ws[(size_t)b * 1024 + j0 + l15] = c_reg[pi];
    }
}

extern "C" void kernel_launch(void* const* d_in, const int* in_sizes, int n_in,
                              void* d_out, int out_size, void* d_ws, size_t ws_size,
                              hipStream_t stream) {
    (void)in_sizes; (void)n_in; (void)out_size;
    const float* Xt = (const float*)d_in[0];
    const float* W[8]; for (int i = 0; i < 8; ++i) W[i] = (const float*)d_in[1 + i];
    const float* Bv[8]; for (int i = 0; i < 8; ++i) Bv[i] = (const float*)d_in[9 + i];
    float* out = (float*)d_out;
    uint8_t* ws = (uint8_t*)d_ws;

    unsigned int*  bar   = (unsigned int*)(ws + 0);           // bar[0], bar[32]
    float*         bias  = (float*)(ws + 256);
    unsigned short* hbuf = (unsigned short*)(ws + 16640);     // [2][64][1024] bf16
    float*         c_ws  = (float*)(ws + 278784);             // [64][1024] fp32
    unsigned short* Wx   = (unsigned short*)(ws + 540928);    // [4096][1024] bf16
    unsigned short* Wh   = (unsigned short*)(ws + 8929536);   // [4096][1024] bf16
    float*         xproj = (float*)(ws + 17318144);           // [T*64][4096] fp32

    size_t avail = ws_size > 17318144 ? ws_size - 17318144 : 0;
    int T = 4;
    for (int t = 1024; t >= 4; t >>= 1)
        if ((size_t)t * 1048576ull <= avail) { T = t; break; }

    init_kernel<<<64, 256, 0, stream>>>(Bv[0], Bv[1], Bv[2], Bv[3], Bv[4], Bv[5], Bv[6], Bv[7],
                                        bias, hbuf, c_ws, bar);
    prep_weights<<<4096, 256, 0, stream>>>(W[0], W[1], W[2], W[3], W[4], W[5], W[6], W[7], Wx, Wh);

    int nch = 1024 / T;
    for (int c = 0; c < nch; ++c) {
        xproj_gemm<<<dim3(32, T / 2), 256, 0, stream>>>(Xt + (size_t)c * T * 65536, Wx, bias, xproj);
        lstm_steps<<<NWG, 256, 0, stream>>>(xproj, hbuf, c_ws, Wh, bar, out, c * T, T);
    }
}